// Round 13
// baseline (140.919 us; speedup 1.0000x reference)
//
#include <hip/hip_runtime.h>
#include <hip/hip_bf16.h>

// Problem constants (B=1 folded out)
#define SDIM 2
#define NPT  6144      // N = H*W
#define CDIM 128
#define H0   64
#define W0   96

// must match builtin signatures: __builtin_amdgcn_fdot2 / cvt_pkrtz use __fp16 vectors
typedef __fp16 half2_t __attribute__((ext_vector_type(2)));

// f16 pyramid level offsets in uint (half2) units
// L0: 2*64*96*64 = 786432 ; L1: 196608 ; L2: 49152 ; L3: 12288
__constant__ int c_lvl_off[4] = {0, 786432, 983040, 1032192};

__device__ __forceinline__ unsigned pack_f16(float a, float b) {
    half2_t h = __builtin_amdgcn_cvt_pkrtz(a, b);
    return __builtin_bit_cast(unsigned, h);
}

__device__ __forceinline__ half2_t as_h2(unsigned u) {
    return __builtin_bit_cast(half2_t, u);
}

// features [S][C][H0*W0] f32  ->  pyr L0 [S][H0*W0][C] f16 (as uint = half2 pairs)
__global__ __launch_bounds__(256) void transpose_kernel(const float* __restrict__ feat,
                                                        unsigned* __restrict__ out) {
    __shared__ float lds[64 * 129];
    const int bid = blockIdx.x;
    const int s = bid / 96;
    const int p0 = (bid % 96) * 64;
    const int tid = threadIdx.x;
    const int sub = tid >> 6;   // 0..3
    const int lane = tid & 63;
#pragma unroll
    for (int k = 0; k < 32; ++k) {
        int c = sub + k * 4;
        lds[lane * 129 + c] = feat[(s * CDIM + c) * (H0 * W0) + p0 + lane];
    }
    __syncthreads();
#pragma unroll
    for (int k = 0; k < 16; ++k) {
        int pl = sub + k * 4;                 // 0..63
        float lo = lds[pl * 129 + lane * 2];
        float hi = lds[pl * 129 + lane * 2 + 1];
        out[(size_t)(s * (H0 * W0) + p0 + pl) * 64 + lane] = pack_f16(lo, hi);
    }
}

// All pyramid levels 1..3 directly from f16 L0 (coalesced: consecutive cp ->
// consecutive addresses). level i = 2^i x 2^i average == cascaded 2x2. f32 accum.
__global__ __launch_bounds__(256) void pool_all_kernel(const unsigned* __restrict__ pyr0,
                                                       unsigned* __restrict__ pyr) {
    int idx = blockIdx.x * 256 + threadIdx.x;
    int lvl, rem;
    if (idx < 196608)      { lvl = 1; rem = idx; }
    else if (idx < 245760) { lvl = 2; rem = idx - 196608; }
    else if (idx < 258048) { lvl = 3; rem = idx - 245760; }
    else return;

    const int m = 1 << lvl;
    const int Wi = W0 >> lvl;
    const int Hi = H0 >> lvl;
    const int cp = rem & 63;
    const int pix = rem >> 6;
    const int x = pix % Wi;
    const int t = pix / Wi;
    const int y = t % Hi;
    const int s = t / Hi;

    const int row_stride = W0 * 64;
    const unsigned* base = pyr0 + ((s * H0 + y * m) * W0 + x * m) * 64 + cp;

    float lo = 0.0f, hi = 0.0f;
    for (int dy = 0; dy < m; ++dy) {
        const unsigned* rp = base + dy * row_stride;
        for (int dx = 0; dx < m; ++dx) {
            half2_t v = as_h2(rp[dx * 64]);
            lo += (float)v.x;
            hi += (float)v.y;
        }
    }
    const float inv = 1.0f / (float)(m * m);
    pyr[c_lvl_off[lvl] + rem] = pack_f16(lo * inv, hi * inv);
}

// One block per (s,n). Wave w = pyramid level w (fully independent: no barriers,
// no shared target stage). 4-lane groups own lattice points.
// Coalesced-group addressing: instruction q reads point + q*64B, lanes k=0..3
// cover contiguous 16B chunks -> 16 distinct 64B segments per wave-instruction,
// each touched once; adjacent groups in a lattice row are contiguous 256B apart.
// XCD-partitioned: xcd = bid & 7; XCDs 0-3 -> s=0, 4-7 -> s=1 (2.09 MiB/XCD L2-resident).
__global__ __launch_bounds__(256) void corr_kernel(const float* __restrict__ targets,
                                                   const float* __restrict__ coords,
                                                   const unsigned* __restrict__ pyr,
                                                   float* __restrict__ out) {
    __shared__ float Ds[4][112];

    const int bid = blockIdx.x;
    const int xcd = bid & 7;
    const int s = xcd >> 2;                       // 0 for XCD 0-3, 1 for XCD 4-7
    const int sn = s * NPT + (bid >> 3) * 4 + (xcd & 3);   // bijective over [0, S*NPT)
    const int tid = threadIdx.x;

    const int lvl = tid >> 6;
    const int lane = tid & 63;
    const int g = lane >> 2;
    const int k = lane & 3;

    const int Wi = W0 >> lvl;
    const int Hi = H0 >> lvl;
    const unsigned* base = pyr + c_lvl_off[lvl] + s * Hi * Wi * 64;

    const float cx = coords[sn * 2 + 0];
    const float cy = coords[sn * 2 + 1];
    const float scale = 1.0f / (float)(1 << lvl);
    const float cxl = cx * scale, cyl = cy * scale;
    const float x0f = floorf(cxl), y0f = floorf(cyl);
    const float wx1 = cxl - x0f, wx0 = 1.0f - wx1;
    const float wy1 = cyl - y0f, wy0 = 1.0f - wy1;
    const int ix0 = (int)x0f - 4;
    const int iy0 = (int)y0f - 4;

    // lane k's target fragments straight from global: instr q covers channels
    // [q*32 + k*8, +8). Lanes sharing k read identical 16B -> L1 broadcast.
    half2_t treg[16];
    const float4* tp = (const float4*)(targets + (size_t)sn * CDIM);
#pragma unroll
    for (int q = 0; q < 4; ++q) {
        float4 va = tp[q * 8 + k * 2 + 0];
        float4 vb = tp[q * 8 + k * 2 + 1];
        treg[q * 4 + 0] = __builtin_amdgcn_cvt_pkrtz(va.x, va.y);
        treg[q * 4 + 1] = __builtin_amdgcn_cvt_pkrtz(va.z, va.w);
        treg[q * 4 + 2] = __builtin_amdgcn_cvt_pkrtz(vb.x, vb.y);
        treg[q * 4 + 3] = __builtin_amdgcn_cvt_pkrtz(vb.z, vb.w);
    }

    for (int it = 0; it < 7; ++it) {
        int p = it * 16 + g;                 // lattice point id, row-major [y][x]
        if (p < 100) {
            int row = (p * 205) >> 11;       // p / 10 (valid for p < 128)
            int col = p - row * 10;
            int y = iy0 + row;
            int x = ix0 + col;
            bool valid = ((unsigned)x < (unsigned)Wi) && ((unsigned)y < (unsigned)Hi);
            int xc = min(max(x, 0), Wi - 1);
            int yc = min(max(y, 0), Hi - 1);
            // point base in uint4 units; lane k instr q -> pb[q*4 + k]
            const uint4* pb = (const uint4*)(base + (yc * Wi + xc) * 64);
            float acc0 = 0.0f, acc1 = 0.0f;
#pragma unroll
            for (int q = 0; q < 4; ++q) {
                uint4 v = pb[q * 4 + k];
                acc0 = __builtin_amdgcn_fdot2(as_h2(v.x), treg[q * 4 + 0], acc0, false);
                acc1 = __builtin_amdgcn_fdot2(as_h2(v.y), treg[q * 4 + 1], acc1, false);
                acc0 = __builtin_amdgcn_fdot2(as_h2(v.z), treg[q * 4 + 2], acc0, false);
                acc1 = __builtin_amdgcn_fdot2(as_h2(v.w), treg[q * 4 + 3], acc1, false);
            }
            float acc = acc0 + acc1;
            acc += __shfl_xor(acc, 1);
            acc += __shfl_xor(acc, 2);
            if (k == 0) Ds[lvl][p] = valid ? acc : 0.0f;
        }
    }

    // Ds[lvl] is wave-private: order LDS writes->reads within the wave (no block barrier;
    // pattern HW-validated in round 8's passing run)
    asm volatile("s_waitcnt lgkmcnt(0)" ::: "memory");

    const float isc = 0.08838834764831843f;  // 1/sqrt(128)
    const size_t obase = (size_t)sn * 324 + lvl * 81;
#pragma unroll
    for (int r = 0; r < 2; ++r) {
        int o = r * 64 + lane;
        if (o < 81) {
            int j = (o * 57) >> 9;           // o / 9  -> x-offset index (outer)
            int i = o - j * 9;               //          y-offset index (inner)
            float d00 = Ds[lvl][i * 10 + j];
            float d01 = Ds[lvl][i * 10 + j + 1];
            float d10 = Ds[lvl][(i + 1) * 10 + j];
            float d11 = Ds[lvl][(i + 1) * 10 + j + 1];
            float v = wy0 * (wx0 * d00 + wx1 * d01) + wy1 * (wx0 * d10 + wx1 * d11);
            out[obase + o] = v * isc;
        }
    }
}

extern "C" void kernel_launch(void* const* d_in, const int* in_sizes, int n_in,
                              void* d_out, int out_size, void* d_ws, size_t ws_size,
                              hipStream_t stream) {
    const float* features = (const float*)d_in[0];   // [1,2,128,64,96]
    const float* targets  = (const float*)d_in[1];   // [1,2,6144,128]
    const float* coords   = (const float*)d_in[2];   // [1,2,6144,2]
    float* out = (float*)d_out;                      // [1,2,6144,324]

    unsigned* pyr = (unsigned*)d_ws;                 // f16 pyramid, 4,177,920 B

    // L0 transpose: [S][C][HW] f32 -> [S][HW][C] f16
    transpose_kernel<<<SDIM * (H0 * W0 / 64), 256, 0, stream>>>(features, pyr);

    // pyramid levels 1..3 from f16 L0 (coalesced)
    pool_all_kernel<<<(258048 + 255) / 256, 256, 0, stream>>>(pyr, pyr);

    // fused correlate + window sample (XCD-partitioned by s)
    corr_kernel<<<SDIM * NPT, 256, 0, stream>>>(targets, coords, pyr, out);
}

// Round 14
// 131.667 us; speedup vs baseline: 1.0703x; 1.0703x over previous
//
#include <hip/hip_runtime.h>
#include <hip/hip_bf16.h>

// Problem constants (B=1 folded out)
#define SDIM 2
#define NPT  6144      // N = H*W
#define CDIM 128
#define H0   64
#define W0   96

// must match builtin signatures: __builtin_amdgcn_fdot2 / cvt_pkrtz use __fp16 vectors
typedef __fp16 half2_t __attribute__((ext_vector_type(2)));

// f16 pyramid level offsets in uint (half2) units
// L0: 2*64*96*64 = 786432 ; L1: 196608 ; L2: 49152 ; L3: 12288
__constant__ int c_lvl_off[4] = {0, 786432, 983040, 1032192};

__device__ __forceinline__ unsigned pack_f16(float a, float b) {
    half2_t h = __builtin_amdgcn_cvt_pkrtz(a, b);
    return __builtin_bit_cast(unsigned, h);
}

__device__ __forceinline__ half2_t as_h2(unsigned u) {
    return __builtin_bit_cast(half2_t, u);
}

// features [S][C][H0*W0] f32  ->  pyr L0 [S][H0*W0][C] f16 (as uint = half2 pairs)
__global__ __launch_bounds__(256) void transpose_kernel(const float* __restrict__ feat,
                                                        unsigned* __restrict__ out) {
    __shared__ float lds[64 * 129];
    const int bid = blockIdx.x;
    const int s = bid / 96;
    const int p0 = (bid % 96) * 64;
    const int tid = threadIdx.x;
    const int sub = tid >> 6;   // 0..3
    const int lane = tid & 63;
#pragma unroll
    for (int k = 0; k < 32; ++k) {
        int c = sub + k * 4;
        lds[lane * 129 + c] = feat[(s * CDIM + c) * (H0 * W0) + p0 + lane];
    }
    __syncthreads();
#pragma unroll
    for (int k = 0; k < 16; ++k) {
        int pl = sub + k * 4;                 // 0..63
        float lo = lds[pl * 129 + lane * 2];
        float hi = lds[pl * 129 + lane * 2 + 1];
        out[(size_t)(s * (H0 * W0) + p0 + pl) * 64 + lane] = pack_f16(lo, hi);
    }
}

// All pyramid levels 1..3 directly from f16 L0 (coalesced: consecutive cp ->
// consecutive addresses). level i = 2^i x 2^i average == cascaded 2x2. f32 accum.
__global__ __launch_bounds__(256) void pool_all_kernel(const unsigned* __restrict__ pyr0,
                                                       unsigned* __restrict__ pyr) {
    int idx = blockIdx.x * 256 + threadIdx.x;
    int lvl, rem;
    if (idx < 196608)      { lvl = 1; rem = idx; }
    else if (idx < 245760) { lvl = 2; rem = idx - 196608; }
    else if (idx < 258048) { lvl = 3; rem = idx - 245760; }
    else return;

    const int m = 1 << lvl;
    const int Wi = W0 >> lvl;
    const int Hi = H0 >> lvl;
    const int cp = rem & 63;
    const int pix = rem >> 6;
    const int x = pix % Wi;
    const int t = pix / Wi;
    const int y = t % Hi;
    const int s = t / Hi;

    const int row_stride = W0 * 64;
    const unsigned* base = pyr0 + ((s * H0 + y * m) * W0 + x * m) * 64 + cp;

    float lo = 0.0f, hi = 0.0f;
    for (int dy = 0; dy < m; ++dy) {
        const unsigned* rp = base + dy * row_stride;
        for (int dx = 0; dx < m; ++dx) {
            half2_t v = as_h2(rp[dx * 64]);
            lo += (float)v.x;
            hi += (float)v.y;
        }
    }
    const float inv = 1.0f / (float)(m * m);
    pyr[c_lvl_off[lvl] + rem] = pack_f16(lo * inv, hi * inv);
}

// One block per (s,n). Wave w = pyramid level w. 4-lane groups own lattice points.
// Coalesced-group addressing: instruction q reads point + q*64B, lanes k=0..3
// covering contiguous 16B chunks -> 16 distinct 64B segments per wave-instruction
// (was 64), each segment touched exactly once across q.
// Target staged via LDS (keeps target traffic off the gather VMEM pipe — round 13
// showed direct-global targets cost +11 µs).
// XCD-partitioned: xcd = bid & 7; XCDs 0-3 -> s=0, 4-7 -> s=1 (2.09 MiB/XCD L2-resident).
__global__ __launch_bounds__(256) void corr_kernel(const float* __restrict__ targets,
                                                   const float* __restrict__ coords,
                                                   const unsigned* __restrict__ pyr,
                                                   float* __restrict__ out) {
    __shared__ __align__(16) float tgt[CDIM];
    __shared__ float Ds[4][112];

    const int bid = blockIdx.x;
    const int xcd = bid & 7;
    const int s = xcd >> 2;                       // 0 for XCD 0-3, 1 for XCD 4-7
    const int sn = s * NPT + (bid >> 3) * 4 + (xcd & 3);   // bijective over [0, S*NPT)
    const int tid = threadIdx.x;

    if (tid < CDIM) tgt[tid] = targets[(size_t)sn * CDIM + tid];
    const float cx = coords[sn * 2 + 0];
    const float cy = coords[sn * 2 + 1];
    __syncthreads();

    const int lvl = tid >> 6;
    const int lane = tid & 63;
    const int g = lane >> 2;
    const int k = lane & 3;

    const int Wi = W0 >> lvl;
    const int Hi = H0 >> lvl;
    const unsigned* base = pyr + c_lvl_off[lvl] + s * Hi * Wi * 64;

    const float scale = 1.0f / (float)(1 << lvl);
    const float cxl = cx * scale, cyl = cy * scale;
    const float x0f = floorf(cxl), y0f = floorf(cyl);
    const float wx1 = cxl - x0f, wx0 = 1.0f - wx1;
    const float wy1 = cyl - y0f, wy0 = 1.0f - wy1;
    const int ix0 = (int)x0f - 4;
    const int iy0 = (int)y0f - 4;

    // lane k's target fragments: instr q covers channels [q*32 + k*8, +8)
    half2_t treg[16];
#pragma unroll
    for (int q = 0; q < 4; ++q)
#pragma unroll
        for (int j = 0; j < 4; ++j) {
            int c = q * 32 + k * 8 + 2 * j;
            treg[q * 4 + j] = __builtin_amdgcn_cvt_pkrtz(tgt[c], tgt[c + 1]);
        }

    for (int it = 0; it < 7; ++it) {
        int p = it * 16 + g;                 // lattice point id, row-major [y][x]
        if (p < 100) {
            int row = (p * 205) >> 11;       // p / 10 (valid for p < 128)
            int col = p - row * 10;
            int y = iy0 + row;
            int x = ix0 + col;
            bool valid = ((unsigned)x < (unsigned)Wi) && ((unsigned)y < (unsigned)Hi);
            int xc = min(max(x, 0), Wi - 1);
            int yc = min(max(y, 0), Hi - 1);
            // point base in uint4 units; lane k instr q -> pb[q*4 + k]
            const uint4* pb = (const uint4*)(base + (yc * Wi + xc) * 64);
            float acc0 = 0.0f, acc1 = 0.0f;
#pragma unroll
            for (int q = 0; q < 4; ++q) {
                uint4 v = pb[q * 4 + k];
                acc0 = __builtin_amdgcn_fdot2(as_h2(v.x), treg[q * 4 + 0], acc0, false);
                acc1 = __builtin_amdgcn_fdot2(as_h2(v.y), treg[q * 4 + 1], acc1, false);
                acc0 = __builtin_amdgcn_fdot2(as_h2(v.z), treg[q * 4 + 2], acc0, false);
                acc1 = __builtin_amdgcn_fdot2(as_h2(v.w), treg[q * 4 + 3], acc1, false);
            }
            float acc = acc0 + acc1;
            acc += __shfl_xor(acc, 1);
            acc += __shfl_xor(acc, 2);
            if (k == 0) Ds[lvl][p] = valid ? acc : 0.0f;
        }
    }

    __syncthreads();

    const float isc = 0.08838834764831843f;  // 1/sqrt(128)
    const size_t obase = (size_t)sn * 324 + lvl * 81;
#pragma unroll
    for (int r = 0; r < 2; ++r) {
        int o = r * 64 + lane;
        if (o < 81) {
            int j = (o * 57) >> 9;           // o / 9  -> x-offset index (outer)
            int i = o - j * 9;               //          y-offset index (inner)
            float d00 = Ds[lvl][i * 10 + j];
            float d01 = Ds[lvl][i * 10 + j + 1];
            float d10 = Ds[lvl][(i + 1) * 10 + j];
            float d11 = Ds[lvl][(i + 1) * 10 + j + 1];
            float v = wy0 * (wx0 * d00 + wx1 * d01) + wy1 * (wx0 * d10 + wx1 * d11);
            out[obase + o] = v * isc;
        }
    }
}

extern "C" void kernel_launch(void* const* d_in, const int* in_sizes, int n_in,
                              void* d_out, int out_size, void* d_ws, size_t ws_size,
                              hipStream_t stream) {
    const float* features = (const float*)d_in[0];   // [1,2,128,64,96]
    const float* targets  = (const float*)d_in[1];   // [1,2,6144,128]
    const float* coords   = (const float*)d_in[2];   // [1,2,6144,2]
    float* out = (float*)d_out;                      // [1,2,6144,324]

    unsigned* pyr = (unsigned*)d_ws;                 // f16 pyramid, 4,177,920 B

    // L0 transpose: [S][C][HW] f32 -> [S][HW][C] f16
    transpose_kernel<<<SDIM * (H0 * W0 / 64), 256, 0, stream>>>(features, pyr);

    // pyramid levels 1..3 from f16 L0 (coalesced)
    pool_all_kernel<<<(258048 + 255) / 256, 256, 0, stream>>>(pyr, pyr);

    // fused correlate + window sample (XCD-partitioned by s)
    corr_kernel<<<SDIM * NPT, 256, 0, stream>>>(targets, coords, pyr, out);
}